// Round 1
// baseline (785.118 us; speedup 1.0000x reference)
//
#include <hip/hip_runtime.h>
#include <math.h>

#define C0 8
#define C1 4
#define NCH 20      // C0 + 3*C1
#define NQ 16
#define KK 5
#define K3 125
#define G 8
#define NZ 512      // 8^3 spatial
#define RMAX 5.5f
#define EPSL 1e-6f

// ---------------- Stage 1: build Wfull[p][q][k][o][c] ----------------
__global__ __launch_bounds__(256) void build_w(
    const float* __restrict__ q_in,   // (16,3)
    const float* __restrict__ q_out,  // (16,3)
    const float* __restrict__ w_ss,   // (8,8,8)
    const float* __restrict__ w_vs,   // (4,8,8)
    const float* __restrict__ w_sv,   // (8,4,8)
    const float* __restrict__ w_vv0,  // (4,4,8)
    const float* __restrict__ w_vv1,  // (4,4,8)
    float* __restrict__ W)
{
    int idx = blockIdx.x * blockDim.x + threadIdx.x;
    const int TOT = NQ * NQ * K3 * NCH * NCH;
    if (idx >= TOT) return;
    int c = idx % NCH;
    int t = idx / NCH;
    int o = t % NCH; t /= NCH;
    int k = t % K3;  t /= K3;
    int q = t % NQ;  int p = t / NQ;

    int kz = k / 25, ky = (k / 5) % 5, kx = k % 5;
    float vz = (float)(kz - 2) - (q_out[p*3+0] - q_in[q*3+0]);
    float vy = (float)(ky - 2) - (q_out[p*3+1] - q_in[q*3+1]);
    float vx = (float)(kx - 2) - (q_out[p*3+2] - q_in[q*3+2]);
    float r  = sqrtf(vz*vz + vy*vy + vx*vx);
    float inv = (r > EPSL) ? (1.0f / r) : 0.0f;
    float uz = vz*inv, uy = vy*inv, ux = vx*inv;

    const float sigma = RMAX / (float)(G - 1);
    float Rg[G];
    #pragma unroll
    for (int g = 0; g < G; ++g) {
        float d = (r - (RMAX * (float)g / (float)(G - 1))) / sigma;
        Rg[g] = __expf(-0.5f * d * d);
    }

    float val;
    if (o < C0) {
        if (c < C0) {  // scalar->scalar
            const float* w = w_ss + (o * C0 + c) * G;
            float s = 0.f;
            #pragma unroll
            for (int g = 0; g < G; ++g) s = fmaf(w[g], Rg[g], s);
            val = s;
        } else {       // vector-in -> scalar-out
            int cv = (c - C0) / 3, j = (c - C0) % 3;
            const float* w = w_sv + (o * C1 + cv) * G;
            float s = 0.f;
            #pragma unroll
            for (int g = 0; g < G; ++g) s = fmaf(w[g], Rg[g], s);
            float uj = (j == 0) ? uz : ((j == 1) ? uy : ux);
            val = s * uj;
        }
    } else {
        int ov = (o - C0) / 3, i = (o - C0) % 3;
        if (c < C0) {  // scalar-in -> vector-out
            const float* w = w_vs + (ov * C0 + c) * G;
            float s = 0.f;
            #pragma unroll
            for (int g = 0; g < G; ++g) s = fmaf(w[g], Rg[g], s);
            float ui = (i == 0) ? uz : ((i == 1) ? uy : ux);
            val = s * ui;
        } else {       // vector -> vector
            int cv = (c - C0) / 3, j = (c - C0) % 3;
            const float* w0 = w_vv0 + (ov * C1 + cv) * G;
            const float* w1 = w_vv1 + (ov * C1 + cv) * G;
            float s0 = 0.f, s1 = 0.f;
            #pragma unroll
            for (int g = 0; g < G; ++g) {
                s0 = fmaf(w0[g], Rg[g], s0);
                s1 = fmaf(w1[g], Rg[g], s1);
            }
            // M_ij = eps[i][m][j] u_m, u = (uz,uy,ux)
            float M;
            if (i == 0)      M = (j == 1) ? -ux : ((j == 2) ?  uy : 0.f);
            else if (i == 1) M = (j == 0) ?  ux : ((j == 2) ? -uz : 0.f);
            else             M = (j == 0) ? -uy : ((j == 1) ?  uz : 0.f);
            val = ((i == j) ? s0 : 0.f) + 0.7071067811865476f * s1 * M;
        }
    }
    W[idx] = val;
}

// ---------------- Stage 2: conv partial[q][o][p][z] ----------------
__global__ __launch_bounds__(256) void conv_stage(
    const float* __restrict__ x,   // [c=20][q=16][512]
    const float* __restrict__ W,   // [p][q][k][o][c]
    float* __restrict__ partial)   // [q][o][p][512]
{
    int tid = threadIdx.x;
    int blk = blockIdx.x;          // ((p*16+q)*2 + zc)
    int zc = blk & 1;
    int q  = (blk >> 1) & 15;
    int p  = blk >> 5;
    int z  = zc * 256 + tid;
    int zz = z >> 6, zy = (z >> 3) & 7, zx = z & 7;

    float acc[NCH];
    #pragma unroll
    for (int o = 0; o < NCH; ++o) acc[o] = 0.f;

    const float* Wpq = W + (size_t)((p * NQ + q) * K3) * (NCH * NCH);
    const float* xq  = x + q * NZ;

    for (int k = 0; k < K3; ++k) {
        int kz = k / 25, ky = (k / 5) % 5, kx = k % 5;
        int iz = zz + kz - 2, iy = zy + ky - 2, ix = zx + kx - 2;
        bool valid = ((unsigned)iz < 8u) & ((unsigned)iy < 8u) & ((unsigned)ix < 8u);
        int zi = (iz << 6) + (iy << 3) + ix;
        float xv[NCH];
        if (valid) {
            #pragma unroll
            for (int c = 0; c < NCH; ++c) xv[c] = xq[c * (NQ * NZ) + zi];
        } else {
            #pragma unroll
            for (int c = 0; c < NCH; ++c) xv[c] = 0.f;
        }
        const float* Wk = Wpq + k * (NCH * NCH);
        #pragma unroll
        for (int o = 0; o < NCH; ++o) {
            #pragma unroll
            for (int c = 0; c < NCH; ++c)
                acc[o] = fmaf(Wk[o * NCH + c], xv[c], acc[o]);
        }
    }
    #pragma unroll
    for (int o = 0; o < NCH; ++o)
        partial[((q * NCH + o) * NQ + p) * NZ + z] = acc[o];
}

// ---------------- Stage 3: reduce over q + bias ----------------
__global__ __launch_bounds__(256) void reduce_stage(
    const float* __restrict__ partial,
    const float* __restrict__ bias,
    float* __restrict__ out)
{
    int idx = blockIdx.x * blockDim.x + threadIdx.x;  // over 20*16*512
    if (idx >= NCH * NQ * NZ) return;
    int o = idx / (NQ * NZ);
    float s = (o < C0) ? bias[o] : 0.f;
    #pragma unroll
    for (int q = 0; q < NQ; ++q) s += partial[q * (NCH * NQ * NZ) + idx];
    out[idx] = s;
}

extern "C" void kernel_launch(void* const* d_in, const int* in_sizes, int n_in,
                              void* d_out, int out_size, void* d_ws, size_t ws_size,
                              hipStream_t stream) {
    const float* x     = (const float*)d_in[0];
    const float* q_in  = (const float*)d_in[1];
    const float* q_out = (const float*)d_in[2];
    const float* w_ss  = (const float*)d_in[3];
    const float* w_vs  = (const float*)d_in[4];
    const float* w_sv  = (const float*)d_in[5];
    const float* w_vv0 = (const float*)d_in[6];
    const float* w_vv1 = (const float*)d_in[7];
    const float* bias  = (const float*)d_in[8];
    float* out = (float*)d_out;

    float* W       = (float*)d_ws;                         // 12.8M floats = 51.2 MB
    float* partial = W + (size_t)NQ * NQ * K3 * NCH * NCH; // 2.62M floats = 10.5 MB

    const int TOT_W = NQ * NQ * K3 * NCH * NCH;            // 12,800,000
    hipLaunchKernelGGL(build_w, dim3((TOT_W + 255) / 256), dim3(256), 0, stream,
                       q_in, q_out, w_ss, w_vs, w_sv, w_vv0, w_vv1, W);

    hipLaunchKernelGGL(conv_stage, dim3(NQ * NQ * 2), dim3(256), 0, stream,
                       x, W, partial);

    hipLaunchKernelGGL(reduce_stage, dim3((NCH * NQ * NZ + 255) / 256), dim3(256), 0, stream,
                       partial, bias, out);
}

// Round 2
// 160.559 us; speedup vs baseline: 4.8899x; 4.8899x over previous
//
#include <hip/hip_runtime.h>
#include <hip/hip_bf16.h>
#include <math.h>

#define C0 8
#define C1 4
#define NCH 20        // C0 + 3*C1
#define NQ 16
#define K3 125
#define G 8
#define NZ 512        // 8^3
#define RMAX 5.5f
#define EPSL 1e-6f

#define M_DIM 320     // (C0+3*C1) * NQ
#define K_DIM 40000   // K3 * NCH * NQ  (order: t, c, q)
#define SPLITS 50     // split-K chunks (1250 k-steps / 50 = 25 steps each)
#define KSTEPS 25     // 32-wide k-steps per chunk
#define PADV 1728     // 12*12*12
#define XTP_C 27648   // PADV * 16 (elements per channel in xtp)

using f32x4 = __attribute__((ext_vector_type(4))) float;
using s16x8 = __attribute__((ext_vector_type(8))) short;

// ---------- geometry table: geo[((p*125+t)*12+j)*16+q], j=0..7 R_g, 8..10 u ----------
__global__ __launch_bounds__(256) void geo_kernel(
    const float* __restrict__ q_in, const float* __restrict__ q_out,
    float* __restrict__ geo)
{
    int gid = blockIdx.x * 256 + threadIdx.x;
    if (gid >= NQ * NQ * K3) return;
    int t = gid % K3; int r0 = gid / K3;
    int q = r0 % NQ;  int p = r0 / NQ;
    int tz = t / 25, ty = (t / 5) % 5, tx = t % 5;
    float vz = (float)(tz - 2) - (q_out[p*3+0] - q_in[q*3+0]);
    float vy = (float)(ty - 2) - (q_out[p*3+1] - q_in[q*3+1]);
    float vx = (float)(tx - 2) - (q_out[p*3+2] - q_in[q*3+2]);
    float r  = sqrtf(vz*vz + vy*vy + vx*vx);
    float inv = (r > EPSL) ? (1.0f / r) : 0.0f;
    const float sigma = RMAX / (float)(G - 1);
    float* gbase = geo + (size_t)(p * K3 + t) * 12 * 16 + q;
    #pragma unroll
    for (int g = 0; g < G; ++g) {
        float d = (r - (RMAX * (float)g / (float)(G - 1))) / sigma;
        gbase[g * 16] = expf(-0.5f * d * d);
    }
    gbase[8 * 16]  = vz * inv;
    gbase[9 * 16]  = vy * inv;
    gbase[10 * 16] = vx * inv;
}

// ---------- padded transposed x: xtp[c][az][ay][ax][q] (bf16) ----------
__global__ __launch_bounds__(256) void xtp_kernel(
    const float* __restrict__ x, __hip_bfloat16* __restrict__ xtp)
{
    int gid = blockIdx.x * 256 + threadIdx.x;
    if (gid >= NCH * PADV * NQ) return;
    int q = gid & 15; int r = gid >> 4;
    int ax = r % 12; r /= 12;
    int ay = r % 12; r /= 12;
    int az = r % 12; int c = r / 12;
    int iz = az - 2, iy = ay - 2, ix = ax - 2;
    bool valid = ((unsigned)iz < 8u) & ((unsigned)iy < 8u) & ((unsigned)ix < 8u);
    float v = valid ? x[((c * NQ + q) << 9) + (iz << 6) + (iy << 3) + ix] : 0.f;
    xtp[gid] = __float2bfloat16(v);
}

// ---------- A matrix (bf16): A[m][t][c][q], m = o*16+p ----------
__global__ __launch_bounds__(256) void build_a(
    const float* __restrict__ geo,
    const float* __restrict__ w_ss, const float* __restrict__ w_vs,
    const float* __restrict__ w_sv, const float* __restrict__ w_vv0,
    const float* __restrict__ w_vv1, __hip_bfloat16* __restrict__ A)
{
    int gid = blockIdx.x * 256 + threadIdx.x;   // grid sized exactly
    int q = gid & 15; int r = gid >> 4;
    int c = r % NCH; r /= NCH;
    int t = r % K3;  int m = r / K3;
    int o = m >> 4;  int p = m & 15;

    const float* gb = geo + (size_t)(p * K3 + t) * 12 * 16 + q;
    float Rg[G];
    #pragma unroll
    for (int g = 0; g < G; ++g) Rg[g] = gb[g * 16];
    float uz = gb[8 * 16], uy = gb[9 * 16], ux = gb[10 * 16];

    float val;
    if (o < C0) {
        if (c < C0) {
            const float* w = w_ss + (o * C0 + c) * G;
            float s = 0.f;
            #pragma unroll
            for (int g = 0; g < G; ++g) s = fmaf(w[g], Rg[g], s);
            val = s;
        } else {
            int cv = (c - C0) / 3, j = (c - C0) % 3;
            const float* w = w_sv + (o * C1 + cv) * G;
            float s = 0.f;
            #pragma unroll
            for (int g = 0; g < G; ++g) s = fmaf(w[g], Rg[g], s);
            float uj = (j == 0) ? uz : ((j == 1) ? uy : ux);
            val = s * uj;
        }
    } else {
        int ov = (o - C0) / 3, i = (o - C0) % 3;
        if (c < C0) {
            const float* w = w_vs + (ov * C0 + c) * G;
            float s = 0.f;
            #pragma unroll
            for (int g = 0; g < G; ++g) s = fmaf(w[g], Rg[g], s);
            float ui = (i == 0) ? uz : ((i == 1) ? uy : ux);
            val = s * ui;
        } else {
            int cv = (c - C0) / 3, j = (c - C0) % 3;
            const float* w0 = w_vv0 + (ov * C1 + cv) * G;
            const float* w1 = w_vv1 + (ov * C1 + cv) * G;
            float s0 = 0.f, s1 = 0.f;
            #pragma unroll
            for (int g = 0; g < G; ++g) {
                s0 = fmaf(w0[g], Rg[g], s0);
                s1 = fmaf(w1[g], Rg[g], s1);
            }
            float Mv;
            if (i == 0)      Mv = (j == 1) ? -ux : ((j == 2) ?  uy : 0.f);
            else if (i == 1) Mv = (j == 0) ?  ux : ((j == 2) ? -uz : 0.f);
            else             Mv = (j == 0) ? -uy : ((j == 1) ?  uz : 0.f);
            val = ((i == j) ? s0 : 0.f) + 0.7071067811865476f * s1 * Mv;
        }
    }
    A[gid] = __float2bfloat16(val);
}

// ---------- MFMA implicit GEMM, split-K -> partial[s][m][z] ----------
__global__ __launch_bounds__(256) void gemm_kernel(
    const short* __restrict__ A, const short* __restrict__ xtp,
    float* __restrict__ partial)
{
    int wave = threadIdx.x >> 6;
    int lane = threadIdx.x & 63;
    int row  = lane & 15;
    int quad = lane >> 4;

    // block -> (s, mb, nb-half); 4 waves of a block share (s, mb) -> A reuse in L1
    int b = blockIdx.x;                  // 0..499
    int s  = b / 10;
    int rr = b % 10;
    int mb = rr >> 1;                    // 0..4
    int nb = (rr & 1) * 4 + wave;        // 0..7

    // per-lane A offsets (elements)
    int aoff[4];
    #pragma unroll
    for (int mt = 0; mt < 4; ++mt)
        aoff[mt] = (mb * 64 + mt * 16 + row) * K_DIM + quad * 8;

    // per-lane B offsets into xtp (elements)
    int boff[4];
    #pragma unroll
    for (int nt = 0; nt < 4; ++nt) {
        int z = nb * 64 + nt * 16 + row;
        int zz = z >> 6, zy = (z >> 3) & 7, zx = z & 7;
        boff[nt] = zz * 2304 + zy * 192 + zx * 16 + (quad & 1) * 8 + (quad >> 1) * XTP_C;
    }

    f32x4 acc[4][4];
    #pragma unroll
    for (int i = 0; i < 4; ++i)
        #pragma unroll
        for (int j = 0; j < 4; ++j) acc[i][j] = (f32x4){0.f, 0.f, 0.f, 0.f};

    int kbase = s * (KSTEPS * 32);
    #pragma unroll 5
    for (int st = 0; st < KSTEPS; ++st) {
        int k0 = kbase + (st << 5);
        int t  = (int)((unsigned)k0 / 320u);
        int c0 = (k0 - t * 320) >> 4;
        int tz = (int)((unsigned)t / 25u);
        int trm = t - tz * 25;
        int ty = (int)((unsigned)trm / 5u);
        int tx = trm - ty * 5;
        int sb = c0 * XTP_C + tz * 2304 + ty * 192 + tx * 16;

        s16x8 a[4], bfr[4];
        #pragma unroll
        for (int mt = 0; mt < 4; ++mt)
            a[mt] = *(const s16x8*)(A + aoff[mt] + k0);
        #pragma unroll
        for (int nt = 0; nt < 4; ++nt)
            bfr[nt] = *(const s16x8*)(xtp + sb + boff[nt]);

        #pragma unroll
        for (int mt = 0; mt < 4; ++mt)
            #pragma unroll
            for (int nt = 0; nt < 4; ++nt)
                acc[mt][nt] = __builtin_amdgcn_mfma_f32_16x16x32_bf16(
                    a[mt], bfr[nt], acc[mt][nt], 0, 0, 0);
    }

    float* pbase = partial + (size_t)s * (M_DIM * NZ);
    #pragma unroll
    for (int mt = 0; mt < 4; ++mt) {
        #pragma unroll
        for (int nt = 0; nt < 4; ++nt) {
            int z = nb * 64 + nt * 16 + row;
            #pragma unroll
            for (int ri = 0; ri < 4; ++ri) {
                int m = mb * 64 + mt * 16 + quad * 4 + ri;
                pbase[m * NZ + z] = acc[mt][nt][ri];
            }
        }
    }
}

// ---------- reduce over splits + bias ----------
__global__ __launch_bounds__(256) void reduce_kernel(
    const float* __restrict__ partial, const float* __restrict__ bias,
    float* __restrict__ out)
{
    int gid = blockIdx.x * 256 + threadIdx.x;   // 320*512
    if (gid >= M_DIM * NZ) return;
    int m = gid >> 9;
    int o = m >> 4;
    float sacc = (o < C0) ? bias[o] : 0.f;
    #pragma unroll 10
    for (int s = 0; s < SPLITS; ++s)
        sacc += partial[gid + s * (M_DIM * NZ)];
    out[gid] = sacc;
}

extern "C" void kernel_launch(void* const* d_in, const int* in_sizes, int n_in,
                              void* d_out, int out_size, void* d_ws, size_t ws_size,
                              hipStream_t stream) {
    const float* x     = (const float*)d_in[0];
    const float* q_in  = (const float*)d_in[1];
    const float* q_out = (const float*)d_in[2];
    const float* w_ss  = (const float*)d_in[3];
    const float* w_vs  = (const float*)d_in[4];
    const float* w_sv  = (const float*)d_in[5];
    const float* w_vv0 = (const float*)d_in[6];
    const float* w_vv1 = (const float*)d_in[7];
    const float* bias  = (const float*)d_in[8];
    float* out = (float*)d_out;

    char* ws = (char*)d_ws;
    __hip_bfloat16* A   = (__hip_bfloat16*)(ws + 0);           // 25,600,000 B
    __hip_bfloat16* xtp = (__hip_bfloat16*)(ws + 25600000);    //  1,105,920 B
    float* geo          = (float*)(ws + 26705920);             //  1,536,000 B
    float* partial      = (float*)(ws + 28241920);             // 32,768,000 B  (total 61.0 MB)

    hipLaunchKernelGGL(geo_kernel, dim3((NQ*NQ*K3 + 255)/256), dim3(256), 0, stream,
                       q_in, q_out, geo);
    hipLaunchKernelGGL(xtp_kernel, dim3((NCH*PADV*NQ + 255)/256), dim3(256), 0, stream,
                       x, xtp);
    hipLaunchKernelGGL(build_a, dim3((M_DIM*K_DIM)/256), dim3(256), 0, stream,
                       geo, w_ss, w_vs, w_sv, w_vv0, w_vv1, A);
    hipLaunchKernelGGL(gemm_kernel, dim3(500), dim3(256), 0, stream,
                       (const short*)A, (const short*)xtp, partial);
    hipLaunchKernelGGL(reduce_kernel, dim3((M_DIM*NZ + 255)/256), dim3(256), 0, stream,
                       partial, bias, out);
}